// Round 1
// baseline (184.074 us; speedup 1.0000x reference)
//
#include <hip/hip_runtime.h>
#include <stdint.h>

#define B_ 64
#define S_ 512
#define EMB_ 256
#define NIN_ 7
#define NOUT_ 4
#define HID_ 512
#define D_ 260            // EMB + NOUT
#define KP_ 288           // D padded to multiple of 32
#define N_ 1024           // z (512) | f (512) gate columns
#define M_ (B_ * S_)      // 32768 rows

typedef __bf16 bf16x8 __attribute__((ext_vector_type(8)));
typedef float floatx4 __attribute__((ext_vector_type(4)));

__device__ __forceinline__ unsigned short f2bf(float f) {
    unsigned u = __float_as_uint(f);
    u += 0x7FFFu + ((u >> 16) & 1u);   // RNE
    return (unsigned short)(u >> 16);
}
__device__ __forceinline__ float bf2f(unsigned short h) {
    return __uint_as_float(((unsigned)h) << 16);
}
__device__ __forceinline__ float sigmoidf_(float x) {
    return 1.0f / (1.0f + __expf(-x));
}
__device__ __forceinline__ float tanhf_(float x) {
    float ax = fabsf(x);
    float e = __expf(-2.0f * ax);
    float t = (1.0f - e) / (1.0f + e);
    return copysignf(t, x);
}

// ---------------- K1a: build c rows (bf16, padded to KP_) ----------------
__global__ void build_c(const float* __restrict__ X, const float* __restrict__ emb,
                        const float* __restrict__ Wn, const float* __restrict__ bn,
                        unsigned short* __restrict__ cB) {
    int r = blockIdx.x;          // 0..M_-1  (r = b*S + s)
    int t = threadIdx.x;         // 0..255
    const float* xr = X + (size_t)r * 8;
    int ev = (int)xr[0];
    cB[(size_t)r * KP_ + t] = f2bf(emb[(size_t)ev * EMB_ + t]);
    if (t < 32) {
        int e = 256 + t;
        float val = 0.0f;
        if (e < D_) {
            int j = e - 256;
            val = bn[j];
#pragma unroll
            for (int i = 0; i < NIN_; ++i) val += xr[1 + i] * Wn[i * NOUT_ + j];
        }
        cB[(size_t)r * KP_ + e] = f2bf(val);
    }
}

// ---------------- K1b: build W^T (bf16): WT[n][k] = Wf[k][n], zero-pad k>=260 --
__global__ void build_wt(const float* __restrict__ Wf, unsigned short* __restrict__ WT) {
    int n = blockIdx.x;          // 0..1023 (cols 0..511 = z, 512..1023 = f)
    for (int k = threadIdx.x; k < KP_; k += blockDim.x) {
        float v = (k < D_) ? Wf[(size_t)k * 1536 + n] : 0.0f;
        WT[(size_t)n * KP_ + k] = f2bf(v);
    }
}

// ---------------- K2: gate GEMM, bf16 MFMA, 128x128 tiles -------------------
__global__ __launch_bounds__(256) void gates_gemm(
    const unsigned short* __restrict__ cB, const unsigned short* __restrict__ WT,
    const float* __restrict__ bias, unsigned short* __restrict__ gates) {
    __shared__ __align__(16) unsigned short As[128 * 32];
    __shared__ __align__(16) unsigned short Bs[128 * 32];
    int mtile = blockIdx.x >> 3;
    int ntile = blockIdx.x & 7;
    int r0 = mtile * 128, n0 = ntile * 128;
    int tid = threadIdx.x;
    int lane = tid & 63, wave = tid >> 6;
    int wm = wave & 1, wn = wave >> 1;
    int lrow = lane >> 2;        // 0..15
    int lchunk = lane & 3;       // 0..3 (16B chunks of 64B k-row)

    floatx4 acc[4][4];
#pragma unroll
    for (int mi = 0; mi < 4; ++mi)
#pragma unroll
        for (int ni = 0; ni < 4; ++ni) acc[mi][ni] = (floatx4){0.f, 0.f, 0.f, 0.f};

    for (int kt = 0; kt < KP_ / 32; ++kt) {
        __syncthreads();
#pragma unroll
        for (int i = 0; i < 2; ++i) {
            int rowb = 32 * wave + 16 * i;     // 16 rows per issue per wave
            const unsigned short* ga = cB + (size_t)(r0 + rowb + lrow) * KP_ + kt * 32 + lchunk * 8;
            __builtin_amdgcn_global_load_lds(
                (const __attribute__((address_space(1))) unsigned int*)ga,
                (__attribute__((address_space(3))) unsigned int*)(As + rowb * 32), 16, 0, 0);
            const unsigned short* gb = WT + (size_t)(n0 + rowb + lrow) * KP_ + kt * 32 + lchunk * 8;
            __builtin_amdgcn_global_load_lds(
                (const __attribute__((address_space(1))) unsigned int*)gb,
                (__attribute__((address_space(3))) unsigned int*)(Bs + rowb * 32), 16, 0, 0);
        }
        __syncthreads();

        bf16x8 af[4], bfr[4];
#pragma unroll
        for (int mi = 0; mi < 4; ++mi)
            af[mi] = *(const bf16x8*)(As + (64 * wm + 16 * mi + (lane & 15)) * 32 + (lane >> 4) * 8);
#pragma unroll
        for (int ni = 0; ni < 4; ++ni)
            bfr[ni] = *(const bf16x8*)(Bs + (64 * wn + 16 * ni + (lane & 15)) * 32 + (lane >> 4) * 8);
#pragma unroll
        for (int mi = 0; mi < 4; ++mi)
#pragma unroll
            for (int ni = 0; ni < 4; ++ni)
                acc[mi][ni] = __builtin_amdgcn_mfma_f32_16x16x32_bf16(af[mi], bfr[ni], acc[mi][ni], 0, 0, 0);
    }

    // epilogue: C/D layout col = lane&15, row = (lane>>4)*4 + reg  [m89/m91]
#pragma unroll
    for (int mi = 0; mi < 4; ++mi) {
        int rbase = r0 + 64 * wm + 16 * mi + (lane >> 4) * 4;
#pragma unroll
        for (int ni = 0; ni < 4; ++ni) {
            int n = n0 + 64 * wn + 16 * ni + (lane & 15);
            float bv = bias[n];
#pragma unroll
            for (int v = 0; v < 4; ++v)
                gates[(size_t)(rbase + v) * N_ + n] = f2bf(acc[mi][ni][v] + bv);
        }
    }
}

// ---------------- K3: chunked scan, 8 chunks of 64 steps --------------------
// PQ[(b*8+chunk)*512 + j] = (P, Q) with h_out = P*h_in + Q over the chunk
__global__ __launch_bounds__(256) void scan_chunks(const unsigned short* __restrict__ gates,
                                                   float* __restrict__ PQ) {
    int blk = blockIdx.x;        // 0..511 : b*8 + chunk
    int b = blk >> 3, chunk = blk & 7;
    int j0 = threadIdx.x * 2;    // two chains per thread
    float P0 = 1.f, Q0 = 0.f, P1 = 1.f, Q1 = 0.f;
    const unsigned short* gz = gates + (size_t)(b * S_ + chunk * 64) * N_ + j0;
    const unsigned short* gf = gz + 512;
#pragma unroll 4
    for (int t = 0; t < 64; ++t) {
        unsigned zz = *(const unsigned*)gz;
        unsigned ff = *(const unsigned*)gf;
        float z0 = tanhf_(bf2f((unsigned short)(zz & 0xffffu)));
        float z1 = tanhf_(bf2f((unsigned short)(zz >> 16)));
        float f0 = sigmoidf_(bf2f((unsigned short)(ff & 0xffffu)));
        float f1 = sigmoidf_(bf2f((unsigned short)(ff >> 16)));
        Q0 = f0 * Q0 + (1.f - f0) * z0; P0 *= f0;
        Q1 = f1 * Q1 + (1.f - f1) * z1; P1 *= f1;
        gz += N_; gf += N_;
    }
    float4 o; o.x = P0; o.y = Q0; o.z = P1; o.w = Q1;
    ((float4*)PQ)[((size_t)blk * 512 + j0) >> 1] = o;
}

// ---------------- K4: init out, fold chunks + backward row + Wo dot ---------
__global__ void out_init(const float* __restrict__ bo, float* __restrict__ out) {
    out[threadIdx.x] = bo[0];
}

__global__ __launch_bounds__(256) void final_out(
    const unsigned short* __restrict__ cB, const float* __restrict__ Wb,
    const float* __restrict__ bb, const float* __restrict__ Wo,
    const float* __restrict__ PQ, float* __restrict__ out) {
    int blk = blockIdx.x;                    // 0..127 (2 blocks per b)
    int b = blk >> 1;
    int jg = (blk & 1) * 256 + threadIdx.x;  // 0..511

    // forward hidden: fold 8 chunk affines in order
    float h = 0.f;
#pragma unroll
    for (int c = 0; c < 8; ++c) {
        float2 pq = ((const float2*)PQ)[(size_t)(b * 8 + c) * 512 + jg];
        h = pq.x * h + pq.y;
    }

    // backward hidden: only s = S-1 matters: hb = (1-sig(gf))*tanh(gz)
    __shared__ float crow[D_];
    for (int k = threadIdx.x; k < D_; k += 256)
        crow[k] = bf2f(cB[(size_t)(b * S_ + (S_ - 1)) * KP_ + k]);
    __syncthreads();
    float gz = bb[jg], gf = bb[512 + jg];
#pragma unroll 4
    for (int k = 0; k < D_; ++k) {
        float cv = crow[k];
        gz += cv * Wb[(size_t)k * 1536 + jg];
        gf += cv * Wb[(size_t)k * 1536 + 512 + jg];
    }
    float hb = (1.f - sigmoidf_(gf)) * tanhf_(gz);

    float partial = h * Wo[jg] + hb * Wo[512 + jg];
    __shared__ float red[256];
    red[threadIdx.x] = partial;
    __syncthreads();
    for (int off = 128; off > 0; off >>= 1) {
        if (threadIdx.x < off) red[threadIdx.x] += red[threadIdx.x + off];
        __syncthreads();
    }
    if (threadIdx.x == 0) atomicAdd(out + b, red[0]);
}

extern "C" void kernel_launch(void* const* d_in, const int* in_sizes, int n_in,
                              void* d_out, int out_size, void* d_ws, size_t ws_size,
                              hipStream_t stream) {
    const float* X   = (const float*)d_in[0];
    const float* emb = (const float*)d_in[1];
    const float* Wn  = (const float*)d_in[2];
    const float* bn  = (const float*)d_in[3];
    const float* Wf  = (const float*)d_in[4];
    const float* bfv = (const float*)d_in[5];
    const float* Wb  = (const float*)d_in[6];
    const float* bb  = (const float*)d_in[7];
    const float* Wo  = (const float*)d_in[8];
    const float* bo  = (const float*)d_in[9];
    float* out = (float*)d_out;

    size_t off_cB = 0;
    size_t off_WT = off_cB + (size_t)M_ * KP_ * 2;   // 18,874,368
    size_t off_g  = off_WT + (size_t)N_ * KP_ * 2;   // +589,824
    size_t off_PQ = off_g  + (size_t)M_ * N_ * 2;    // +67,108,864
    size_t need   = off_PQ + (size_t)B_ * 8 * 512 * 2 * sizeof(float);
    if (ws_size < need) return;  // diagnostic: output stays poisoned

    unsigned short* cB    = (unsigned short*)((char*)d_ws + off_cB);
    unsigned short* WT    = (unsigned short*)((char*)d_ws + off_WT);
    unsigned short* gates = (unsigned short*)((char*)d_ws + off_g);
    float*          PQ    = (float*)((char*)d_ws + off_PQ);

    build_c<<<M_, 256, 0, stream>>>(X, emb, Wn, bn, cB);
    build_wt<<<N_, 256, 0, stream>>>(Wf, WT);
    out_init<<<1, 64, 0, stream>>>(bo, out);
    gates_gemm<<<2048, 256, 0, stream>>>(cB, WT, bfv, gates);
    scan_chunks<<<512, 256, 0, stream>>>(gates, PQ);
    final_out<<<128, 256, 0, stream>>>(cB, Wb, bb, Wo, PQ, out);
}

// Round 2
// 151.586 us; speedup vs baseline: 1.2143x; 1.2143x over previous
//
#include <hip/hip_runtime.h>
#include <stdint.h>

#define B_ 64
#define S_ 512
#define EMB_ 256
#define NIN_ 7
#define NOUT_ 4
#define HID_ 512
#define D_ 260            // EMB + NOUT
#define KP_ 288           // D padded to multiple of 32
#define M_ (B_ * S_)      // 32768 rows
// virtual gate cols: 1024 total; ntile covers 64 j's: local col <64 = z, >=64 = f

typedef __bf16 bf16x8 __attribute__((ext_vector_type(8)));
typedef float floatx4 __attribute__((ext_vector_type(4)));
typedef unsigned short u16x8 __attribute__((ext_vector_type(8)));

__device__ __forceinline__ unsigned short f2bf(float f) {
    unsigned u = __float_as_uint(f);
    u += 0x7FFFu + ((u >> 16) & 1u);   // RNE
    return (unsigned short)(u >> 16);
}
__device__ __forceinline__ float bf2f(unsigned short h) {
    return __uint_as_float(((unsigned)h) << 16);
}
__device__ __forceinline__ float rcp_(float x) { return __builtin_amdgcn_rcpf(x); }
__device__ __forceinline__ float sigmoidf_(float x) {
    return rcp_(1.0f + __expf(-x));
}
__device__ __forceinline__ float tanhf_(float x) {
    float ax = fabsf(x);
    float e = __expf(-2.0f * ax);
    float t = (1.0f - e) * rcp_(1.0f + e);
    return copysignf(t, x);
}

// ---------------- K1: fused prep: build cB, build WT2, init out -------------
// roles by blockIdx: [0,8192) build_c (4 rows each); [8192,8448) WT2 (4 v-rows
// each); 8448: out init.
__global__ __launch_bounds__(256) void prep(
    const float* __restrict__ X, const float* __restrict__ emb,
    const float* __restrict__ Wn, const float* __restrict__ bn,
    const float* __restrict__ Wf, const float* __restrict__ bo,
    unsigned short* __restrict__ cB, unsigned short* __restrict__ WT2,
    float* __restrict__ out) {
    int bid = blockIdx.x;
    int tid = threadIdx.x;
    int wave = tid >> 6, lane = tid & 63;

    if (bid < 8192) {                       // ---- build c rows, bf16, pad KP_
        int r = bid * 4 + wave;
        const float* xr = X + (size_t)r * 8;
        int ev = (int)xr[0];
        float4 e4 = *(const float4*)(emb + (size_t)ev * EMB_ + lane * 4);
        unsigned short p[4] = {f2bf(e4.x), f2bf(e4.y), f2bf(e4.z), f2bf(e4.w)};
        *(uint2*)(cB + (size_t)r * KP_ + lane * 4) = *(const uint2*)p;
        if (lane < 16) {                    // tail cols 256..287 (4 real + pad)
            unsigned short a0 = 0, a1 = 0;
            int e0 = 2 * lane;
            if (e0 < NOUT_) {
                float v = bn[e0];
#pragma unroll
                for (int i = 0; i < NIN_; ++i) v += xr[1 + i] * Wn[i * NOUT_ + e0];
                a0 = f2bf(v);
            }
            int e1 = e0 + 1;
            if (e1 < NOUT_) {
                float v = bn[e1];
#pragma unroll
                for (int i = 0; i < NIN_; ++i) v += xr[1 + i] * Wn[i * NOUT_ + e1];
                a1 = f2bf(v);
            }
            *(unsigned*)(cB + (size_t)r * KP_ + 256 + 2 * lane) =
                (unsigned)a0 | ((unsigned)a1 << 16);
        }
    } else if (bid < 8448) {                // ---- WT2[v][k] (bf16, pad K)
        int v = (bid - 8192) * 4 + wave;    // 0..1023 virtual col
        int r7 = v & 127;
        int j = (v >> 7) * 64 + (r7 & 63);
        int col = (r7 < 64) ? j : (512 + j);   // Wf column
        // lane covers k = 4*lane .. +3; lanes<8 also k = 256+4*lane .. +3
        int k0 = 4 * lane;
        unsigned short p[4];
#pragma unroll
        for (int q = 0; q < 4; ++q) {
            int k = k0 + q;
            p[q] = (k < D_) ? f2bf(Wf[(size_t)k * 1536 + col]) : (unsigned short)0;
        }
        *(uint2*)(WT2 + (size_t)v * KP_ + k0) = *(const uint2*)p;
        if (lane < 8) {
            int kb = 256 + 4 * lane;
#pragma unroll
            for (int q = 0; q < 4; ++q) {
                int k = kb + q;
                p[q] = (k < D_) ? f2bf(Wf[(size_t)k * 1536 + col]) : (unsigned short)0;
            }
            *(uint2*)(WT2 + (size_t)v * KP_ + kb) = *(const uint2*)p;
        }
    } else {                                // ---- init out to bo
        if (tid < B_) out[tid] = bo[0];
    }
}

// ---------------- K2: fused GEMM + in-LDS chunk scan ------------------------
// grid 2048: mtile = bid%256 (XCD = mtile%8 keeps cB panel set in L2),
// ntile = bid/256 (64 j's). Emits PQ[(b*4+chunk)*512 + jglob] = (P,Q).
__global__ __launch_bounds__(256) void gemm_scan(
    const unsigned short* __restrict__ cB, const unsigned short* __restrict__ WT2,
    const float* __restrict__ bias, float* __restrict__ PQ) {
    __shared__ __align__(16) unsigned short As[128 * 32];
    __shared__ __align__(16) unsigned short Bs[128 * 32];
    __shared__ __align__(16) unsigned short Gt[128 * 136];  // [col][row+pad]
    int bid = blockIdx.x;
    int mtile = bid & 255;
    int ntile = bid >> 8;
    int r0 = mtile * 128;
    int n0 = ntile * 128;                   // virtual col base
    int tid = threadIdx.x;
    int lane = tid & 63, wave = tid >> 6;
    int wm = wave & 1, wn = wave >> 1;
    int rl = lane & 15;                     // frag row/col within 16
    int kc = lane >> 4;                     // k-chunk 0..3
    int sw = kc ^ ((rl >> 1) & 3);          // swizzled LDS slot for reads
    // staging fetch: lane L -> LDS slot L; fetch global chunk c = swizzle
    int l_r = lane >> 2;                    // row within 16-row issue
    int l_c = (lane & 3) ^ ((lane >> 3) & 3);  // swizzled global chunk

    floatx4 acc[4][4];
#pragma unroll
    for (int mi = 0; mi < 4; ++mi)
#pragma unroll
        for (int ni = 0; ni < 4; ++ni) acc[mi][ni] = (floatx4){0.f, 0.f, 0.f, 0.f};

    for (int kt = 0; kt < KP_ / 32; ++kt) {
        __syncthreads();
#pragma unroll
        for (int i = 0; i < 2; ++i) {
            int rowb = 32 * wave + 16 * i;
            const unsigned short* ga =
                cB + (size_t)(r0 + rowb + l_r) * KP_ + kt * 32 + l_c * 8;
            __builtin_amdgcn_global_load_lds(
                (const __attribute__((address_space(1))) unsigned int*)ga,
                (__attribute__((address_space(3))) unsigned int*)(As + rowb * 32), 16, 0, 0);
            const unsigned short* gb =
                WT2 + (size_t)(n0 + rowb + l_r) * KP_ + kt * 32 + l_c * 8;
            __builtin_amdgcn_global_load_lds(
                (const __attribute__((address_space(1))) unsigned int*)gb,
                (__attribute__((address_space(3))) unsigned int*)(Bs + rowb * 32), 16, 0, 0);
        }
        __syncthreads();

        bf16x8 af[4], bfr[4];
#pragma unroll
        for (int mi = 0; mi < 4; ++mi)
            af[mi] = *(const bf16x8*)(As + (64 * wm + 16 * mi + rl) * 32 + sw * 8);
#pragma unroll
        for (int ni = 0; ni < 4; ++ni)
            bfr[ni] = *(const bf16x8*)(Bs + (64 * wn + 16 * ni + rl) * 32 + sw * 8);
#pragma unroll
        for (int mi = 0; mi < 4; ++mi)
#pragma unroll
            for (int ni = 0; ni < 4; ++ni)
                acc[mi][ni] = __builtin_amdgcn_mfma_f32_16x16x32_bf16(af[mi], bfr[ni], acc[mi][ni], 0, 0, 0);
    }

    // ---- epilogue: bias + bf16 -> Gt[col][row] (transposed, row-stride 136)
    // C/D: col = lane&15, row = (lane>>4)*4 + reg  [m89/m91]
#pragma unroll
    for (int ni = 0; ni < 4; ++ni) {
        int lc = 64 * wn + 16 * ni + rl;       // local virtual col 0..127
        int jg = ntile * 64 + (lc & 63);
        float bv = (lc < 64) ? bias[jg] : bias[512 + jg];
#pragma unroll
        for (int mi = 0; mi < 4; ++mi) {
            int lrb = 64 * wm + 16 * mi + (lane >> 4) * 4;  // local row base
            unsigned short p[4];
#pragma unroll
            for (int v = 0; v < 4; ++v) p[v] = f2bf(acc[mi][ni][v] + bv);
            *(uint2*)(Gt + (size_t)lc * 136 + lrb) = *(const uint2*)p;
        }
    }
    __syncthreads();

    // ---- scan: thread = (subchunk c = tid>>6, j = tid&63); 32 steps each
    {
        int j = tid & 63, c = tid >> 6;
        float P = 1.f, Q = 0.f;
        const unsigned short* zp = Gt + (size_t)j * 136 + c * 32;
        const unsigned short* fp = Gt + (size_t)(64 + j) * 136 + c * 32;
#pragma unroll
        for (int u = 0; u < 4; ++u) {
            u16x8 zv = *(const u16x8*)(zp + 8 * u);
            u16x8 fv = *(const u16x8*)(fp + 8 * u);
#pragma unroll
            for (int t = 0; t < 8; ++t) {
                float z = tanhf_(bf2f(zv[t]));
                float f = sigmoidf_(bf2f(fv[t]));
                Q = f * Q + (1.f - f) * z;
                P *= f;
            }
        }
        float* Sp = (float*)As;             // reuse staging (2 KB of 8 KB)
        Sp[tid] = P;
        Sp[256 + tid] = Q;
        __syncthreads();
        if (tid < 64) {
            float Pt = 1.f, Qt = 0.f;
#pragma unroll
            for (int cc = 0; cc < 4; ++cc) {
                float p = Sp[cc * 64 + tid];
                float q = Sp[256 + cc * 64 + tid];
                Qt = p * Qt + q;
                Pt *= p;
            }
            int b = r0 >> 9;
            int chm = (r0 >> 7) & 3;
            size_t idx = ((size_t)(b * 4 + chm) * 512 + ntile * 64 + tid);
            ((float2*)PQ)[idx] = make_float2(Pt, Qt);
        }
    }
}

// ---------------- K3: fold chunks + backward row + Wo dot -------------------
__global__ __launch_bounds__(256) void final_out(
    const unsigned short* __restrict__ cB, const float* __restrict__ Wb,
    const float* __restrict__ bb, const float* __restrict__ Wo,
    const float* __restrict__ PQ, float* __restrict__ out) {
    int blk = blockIdx.x;                    // 0..127 (2 blocks per b)
    int b = blk >> 1;
    int jg = (blk & 1) * 256 + threadIdx.x;  // 0..511

    float h = 0.f;
#pragma unroll
    for (int c = 0; c < 4; ++c) {
        float2 pq = ((const float2*)PQ)[(size_t)(b * 4 + c) * 512 + jg];
        h = pq.x * h + pq.y;
    }

    __shared__ float crow[D_];
    for (int k = threadIdx.x; k < D_; k += 256)
        crow[k] = bf2f(cB[(size_t)(b * S_ + (S_ - 1)) * KP_ + k]);
    __syncthreads();
    float gz = bb[jg], gf = bb[512 + jg];
#pragma unroll 4
    for (int k = 0; k < D_; ++k) {
        float cv = crow[k];
        gz += cv * Wb[(size_t)k * 1536 + jg];
        gf += cv * Wb[(size_t)k * 1536 + 512 + jg];
    }
    float hb = (1.f - sigmoidf_(gf)) * tanhf_(gz);

    float partial = h * Wo[jg] + hb * Wo[512 + jg];
    __shared__ float red[256];
    red[threadIdx.x] = partial;
    __syncthreads();
    for (int off = 128; off > 0; off >>= 1) {
        if (threadIdx.x < off) red[threadIdx.x] += red[threadIdx.x + off];
        __syncthreads();
    }
    if (threadIdx.x == 0) atomicAdd(out + b, red[0]);
}

extern "C" void kernel_launch(void* const* d_in, const int* in_sizes, int n_in,
                              void* d_out, int out_size, void* d_ws, size_t ws_size,
                              hipStream_t stream) {
    const float* X   = (const float*)d_in[0];
    const float* emb = (const float*)d_in[1];
    const float* Wn  = (const float*)d_in[2];
    const float* bn  = (const float*)d_in[3];
    const float* Wf  = (const float*)d_in[4];
    const float* bfv = (const float*)d_in[5];
    const float* Wb  = (const float*)d_in[6];
    const float* bb  = (const float*)d_in[7];
    const float* Wo  = (const float*)d_in[8];
    const float* bo  = (const float*)d_in[9];
    float* out = (float*)d_out;

    size_t off_cB = 0;
    size_t off_WT = off_cB + (size_t)M_ * KP_ * 2;           // 18,874,368
    size_t off_PQ = off_WT + (size_t)1024 * KP_ * 2;         // +589,824
    size_t need   = off_PQ + (size_t)B_ * 4 * 512 * 2 * sizeof(float);  // +1 MB
    if (ws_size < need) return;

    unsigned short* cB  = (unsigned short*)((char*)d_ws + off_cB);
    unsigned short* WT2 = (unsigned short*)((char*)d_ws + off_WT);
    float*          PQ  = (float*)((char*)d_ws + off_PQ);

    prep<<<8449, 256, 0, stream>>>(X, emb, Wn, bn, Wf, bo, cB, WT2, out);
    gemm_scan<<<2048, 256, 0, stream>>>(cB, WT2, bfv, PQ);
    final_out<<<128, 256, 0, stream>>>(cB, Wb, bb, Wo, PQ, out);
}

// Round 3
// 146.283 us; speedup vs baseline: 1.2583x; 1.0363x over previous
//
#include <hip/hip_runtime.h>
#include <stdint.h>

#define B_ 64
#define S_ 512
#define EMB_ 256
#define NIN_ 7
#define NOUT_ 4
#define HID_ 512
#define D_ 260            // EMB + NOUT
#define KP_ 288           // D padded; col 260 = 1.0 (bias row), 261.. = 0
#define M_ (B_ * S_)      // 32768 rows

typedef __bf16 bf16x8 __attribute__((ext_vector_type(8)));
typedef float floatx4 __attribute__((ext_vector_type(4)));
typedef unsigned short u16x4 __attribute__((ext_vector_type(4)));

__device__ __forceinline__ unsigned short f2bf(float f) {
    unsigned u = __float_as_uint(f);
    u += 0x7FFFu + ((u >> 16) & 1u);   // RNE
    return (unsigned short)(u >> 16);
}
__device__ __forceinline__ float bf2f(unsigned short h) {
    return __uint_as_float(((unsigned)h) << 16);
}
__device__ __forceinline__ float rcp_(float x) { return __builtin_amdgcn_rcpf(x); }
__device__ __forceinline__ float sigmoidf_(float x) {
    return rcp_(1.0f + __expf(-x));
}
__device__ __forceinline__ float tanhf_(float x) {
    float ax = fabsf(x);
    float e = __expf(-2.0f * ax);
    float t = (1.0f - e) * rcp_(1.0f + e);
    return copysignf(t, x);
}

// ---------------- K1: fused prep: build cB, build WT2 (bias in K), init out --
__global__ __launch_bounds__(256) void prep(
    const float* __restrict__ X, const float* __restrict__ emb,
    const float* __restrict__ Wn, const float* __restrict__ bn,
    const float* __restrict__ Wf, const float* __restrict__ bfv,
    const float* __restrict__ bo,
    unsigned short* __restrict__ cB, unsigned short* __restrict__ WT2,
    float* __restrict__ out) {
    int bid = blockIdx.x;
    int tid = threadIdx.x;
    int wave = tid >> 6, lane = tid & 63;

    if (bid < 8192) {                       // ---- build c rows, bf16, pad KP_
        int r = bid * 4 + wave;
        const float* xr = X + (size_t)r * 8;
        int ev = (int)xr[0];
        float4 e4 = *(const float4*)(emb + (size_t)ev * EMB_ + lane * 4);
        unsigned short p[4] = {f2bf(e4.x), f2bf(e4.y), f2bf(e4.z), f2bf(e4.w)};
        *(uint2*)(cB + (size_t)r * KP_ + lane * 4) = *(const uint2*)p;
        if (lane < 16) {                    // tail cols 256..287
            unsigned short a0 = 0, a1 = 0;
            int e0 = 256 + 2 * lane;
#pragma unroll
            for (int h = 0; h < 2; ++h) {
                int e = e0 + h;
                unsigned short res = 0;
                if (e < D_) {
                    int j = e - 256;
                    float v = bn[j];
#pragma unroll
                    for (int i = 0; i < NIN_; ++i) v += xr[1 + i] * Wn[i * NOUT_ + j];
                    res = f2bf(v);
                } else if (e == D_) {
                    res = 0x3F80;           // 1.0 -> picks up bias row of WT2
                }
                if (h == 0) a0 = res; else a1 = res;
            }
            *(unsigned*)(cB + (size_t)r * KP_ + e0) =
                (unsigned)a0 | ((unsigned)a1 << 16);
        }
    } else if (bid < 8448) {                // ---- WT2[v][k] (bf16, pad K)
        int v = (bid - 8192) * 4 + wave;    // 0..1023 virtual col
        int r7 = v & 127;
        int j = (v >> 7) * 64 + (r7 & 63);
        int col = (r7 < 64) ? j : (512 + j);   // Wf/bias column
        int k0 = 4 * lane;
        unsigned short p[4];
#pragma unroll
        for (int q = 0; q < 4; ++q) {
            int k = k0 + q;
            p[q] = (k < D_) ? f2bf(Wf[(size_t)k * 1536 + col])
                 : (k == D_) ? f2bf(bfv[col]) : (unsigned short)0;
        }
        *(uint2*)(WT2 + (size_t)v * KP_ + k0) = *(const uint2*)p;
        if (lane < 8) {
            int kb = 256 + 4 * lane;
#pragma unroll
            for (int q = 0; q < 4; ++q) {
                int k = kb + q;
                p[q] = (k < D_) ? f2bf(Wf[(size_t)k * 1536 + col])
                     : (k == D_) ? f2bf(bfv[col]) : (unsigned short)0;
            }
            *(uint2*)(WT2 + (size_t)v * KP_ + kb) = *(const uint2*)p;
        }
    } else {                                // ---- init out to bo
        if (tid < B_) out[tid] = bo[0];
    }
}

// ---------------- K2: fused GEMM + in-LDS chunk scan ------------------------
// grid 2048: mtile = bid%256 (XCD L2 locality), ntile = bid/256 (64 j's).
// K-loop: 3 stages x 3 k-tiles, single barrier pair per stage.
// LDS union: 49.2 KB staging; Gt (128 x stride-132 bf16, 33.8 KB) + scan
// scratch alias it after the K-loop.
__global__ __launch_bounds__(256) void gemm_scan(
    const unsigned short* __restrict__ cB, const unsigned short* __restrict__ WT2,
    float* __restrict__ PQ) {
    __shared__ __align__(16) unsigned short L[24576];      // 49,152 B
    int bid = blockIdx.x;
    int mtile = bid & 255;
    int ntile = bid >> 8;
    int r0 = mtile * 128;
    int n0 = ntile * 128;                   // virtual col base
    int tid = threadIdx.x;
    int lane = tid & 63, wave = tid >> 6;
    int wm = wave & 1, wn = wave >> 1;
    int rl = lane & 15;
    int kc = lane >> 4;
    int sw = kc ^ ((rl >> 1) & 3);          // swizzled LDS k-chunk for reads
    int l_r = lane >> 2;                    // staging row within 16-row issue
    int l_c = (lane & 3) ^ ((lane >> 3) & 3);  // swizzled global k-chunk

    floatx4 acc[4][4];
#pragma unroll
    for (int mi = 0; mi < 4; ++mi)
#pragma unroll
        for (int ni = 0; ni < 4; ++ni) acc[mi][ni] = (floatx4){0.f, 0.f, 0.f, 0.f};

    for (int st = 0; st < 3; ++st) {
        __syncthreads();                    // previous stage's LDS reads done
#pragma unroll
        for (int q = 0; q < 3; ++q) {
            int kt = st * 3 + q;
            unsigned short* As = L + q * 8192;
            unsigned short* Bs = As + 4096;
#pragma unroll
            for (int i = 0; i < 2; ++i) {
                int rowb = 32 * wave + 16 * i;
                const unsigned short* ga =
                    cB + (size_t)(r0 + rowb + l_r) * KP_ + kt * 32 + l_c * 8;
                __builtin_amdgcn_global_load_lds(
                    (const __attribute__((address_space(1))) unsigned int*)ga,
                    (__attribute__((address_space(3))) unsigned int*)(As + rowb * 32), 16, 0, 0);
                const unsigned short* gb =
                    WT2 + (size_t)(n0 + rowb + l_r) * KP_ + kt * 32 + l_c * 8;
                __builtin_amdgcn_global_load_lds(
                    (const __attribute__((address_space(1))) unsigned int*)gb,
                    (__attribute__((address_space(3))) unsigned int*)(Bs + rowb * 32), 16, 0, 0);
            }
        }
        __syncthreads();                    // drains vmcnt: stage resident
#pragma unroll
        for (int q = 0; q < 3; ++q) {
            const unsigned short* As = L + q * 8192;
            const unsigned short* Bs = As + 4096;
            bf16x8 af[4], bfr[4];
#pragma unroll
            for (int mi = 0; mi < 4; ++mi)
                af[mi] = *(const bf16x8*)(As + (64 * wm + 16 * mi + rl) * 32 + sw * 8);
#pragma unroll
            for (int ni = 0; ni < 4; ++ni)
                bfr[ni] = *(const bf16x8*)(Bs + (64 * wn + 16 * ni + rl) * 32 + sw * 8);
#pragma unroll
            for (int mi = 0; mi < 4; ++mi)
#pragma unroll
                for (int ni = 0; ni < 4; ++ni)
                    acc[mi][ni] = __builtin_amdgcn_mfma_f32_16x16x32_bf16(af[mi], bfr[ni], acc[mi][ni], 0, 0, 0);
        }
    }
    __syncthreads();                        // all MFMA LDS reads done

    // ---- epilogue: pack acc -> Gt[col][row], stride 132 (aliases staging)
    // C/D: col = lane&15, row = (lane>>4)*4 + reg  [m89/m91]
#pragma unroll
    for (int ni = 0; ni < 4; ++ni) {
        int lc = 64 * wn + 16 * ni + rl;       // local virtual col 0..127
#pragma unroll
        for (int mi = 0; mi < 4; ++mi) {
            int lrb = 64 * wm + 16 * mi + (lane >> 4) * 4;
            unsigned short p[4];
#pragma unroll
            for (int v = 0; v < 4; ++v) p[v] = f2bf(acc[mi][ni][v]);
            *(uint2*)(L + (size_t)lc * 132 + lrb) = *(const uint2*)p;
        }
    }
    __syncthreads();

    // ---- scan: thread (c = tid>>6, j = tid&63) scans subchunk c' (32 steps)
    {
        int j = tid & 63, c = tid >> 6;
        int cp = (c + (j >> 4)) & 3;        // permuted subchunk: 2-way banks
        float P = 1.f, Q = 0.f;
        const unsigned short* zp = L + (size_t)j * 132 + cp * 32;
        const unsigned short* fp = L + (size_t)(64 + j) * 132 + cp * 32;
#pragma unroll
        for (int u = 0; u < 8; ++u) {
            u16x4 zv = *(const u16x4*)(zp + 4 * u);
            u16x4 fv = *(const u16x4*)(fp + 4 * u);
#pragma unroll
            for (int t = 0; t < 4; ++t) {
                float z = tanhf_(bf2f(zv[t]));
                float f = sigmoidf_(bf2f(fv[t]));
                Q = f * Q + (1.f - f) * z;
                P *= f;
            }
        }
        float* SpP = (float*)((char*)L + 36864);   // past Gt (33,792 B)
        float* SpQ = SpP + 256;
        SpP[cp * 64 + j] = P;
        SpQ[cp * 64 + j] = Q;
        __syncthreads();
        if (tid < 64) {
            float Pt = 1.f, Qt = 0.f;
#pragma unroll
            for (int cc = 0; cc < 4; ++cc) {
                float p = SpP[cc * 64 + tid];
                float q = SpQ[cc * 64 + tid];
                Qt = p * Qt + q;
                Pt *= p;
            }
            int b = r0 >> 9;
            int chm = (r0 >> 7) & 3;
            size_t idx = ((size_t)(b * 4 + chm) * 512 + ntile * 64 + tid);
            ((float2*)PQ)[idx] = make_float2(Pt, Qt);
        }
    }
}

// ---------------- K3: fold chunks + backward row + Wo dot -------------------
__global__ __launch_bounds__(256) void final_out(
    const unsigned short* __restrict__ cB, const float* __restrict__ Wb,
    const float* __restrict__ bb, const float* __restrict__ Wo,
    const float* __restrict__ PQ, float* __restrict__ out) {
    int blk = blockIdx.x;                    // 0..127 (2 blocks per b)
    int b = blk >> 1;
    int jg = (blk & 1) * 256 + threadIdx.x;  // 0..511

    float h = 0.f;
#pragma unroll
    for (int c = 0; c < 4; ++c) {
        float2 pq = ((const float2*)PQ)[(size_t)(b * 4 + c) * 512 + jg];
        h = pq.x * h + pq.y;
    }

    __shared__ float crow[D_];
    for (int k = threadIdx.x; k < D_; k += 256)
        crow[k] = bf2f(cB[(size_t)(b * S_ + (S_ - 1)) * KP_ + k]);
    __syncthreads();
    float gz = bb[jg], gf = bb[512 + jg];
#pragma unroll 4
    for (int k = 0; k < D_; ++k) {
        float cv = crow[k];
        gz += cv * Wb[(size_t)k * 1536 + jg];
        gf += cv * Wb[(size_t)k * 1536 + 512 + jg];
    }
    float hb = (1.f - sigmoidf_(gf)) * tanhf_(gz);

    float partial = h * Wo[jg] + hb * Wo[512 + jg];
    __shared__ float red[256];
    red[threadIdx.x] = partial;
    __syncthreads();
    for (int off = 128; off > 0; off >>= 1) {
        if (threadIdx.x < off) red[threadIdx.x] += red[threadIdx.x + off];
        __syncthreads();
    }
    if (threadIdx.x == 0) atomicAdd(out + b, red[0]);
}

extern "C" void kernel_launch(void* const* d_in, const int* in_sizes, int n_in,
                              void* d_out, int out_size, void* d_ws, size_t ws_size,
                              hipStream_t stream) {
    const float* X   = (const float*)d_in[0];
    const float* emb = (const float*)d_in[1];
    const float* Wn  = (const float*)d_in[2];
    const float* bn  = (const float*)d_in[3];
    const float* Wf  = (const float*)d_in[4];
    const float* bfv = (const float*)d_in[5];
    const float* Wb  = (const float*)d_in[6];
    const float* bb  = (const float*)d_in[7];
    const float* Wo  = (const float*)d_in[8];
    const float* bo  = (const float*)d_in[9];
    float* out = (float*)d_out;

    size_t off_cB = 0;
    size_t off_WT = off_cB + (size_t)M_ * KP_ * 2;           // 18,874,368
    size_t off_PQ = off_WT + (size_t)1024 * KP_ * 2;         // +589,824
    size_t need   = off_PQ + (size_t)B_ * 4 * 512 * 2 * sizeof(float);  // +1 MB
    if (ws_size < need) return;

    unsigned short* cB  = (unsigned short*)((char*)d_ws + off_cB);
    unsigned short* WT2 = (unsigned short*)((char*)d_ws + off_WT);
    float*          PQ  = (float*)((char*)d_ws + off_PQ);

    prep<<<8449, 256, 0, stream>>>(X, emb, Wn, bn, Wf, bfv, bo, cB, WT2, out);
    gemm_scan<<<2048, 256, 0, stream>>>(cB, WT2, PQ);
    final_out<<<128, 256, 0, stream>>>(cB, Wb, bb, Wo, PQ, out);
}

// Round 4
// 128.044 us; speedup vs baseline: 1.4376x; 1.1424x over previous
//
#include <hip/hip_runtime.h>
#include <stdint.h>

#define B_ 64
#define S_ 512
#define EMB_ 256
#define NIN_ 7
#define NOUT_ 4
#define HID_ 512
#define D_ 260            // EMB + NOUT
#define KP_ 288           // K padded; k==260 carries 1.0/bias row
#define M_ (B_ * S_)      // 32768 rows

typedef __bf16 bf16x8 __attribute__((ext_vector_type(8)));
typedef float floatx4 __attribute__((ext_vector_type(4)));
typedef unsigned short u16x4 __attribute__((ext_vector_type(4)));
typedef unsigned short u16x8 __attribute__((ext_vector_type(8)));

__device__ __forceinline__ unsigned short f2bf(float f) {
    unsigned u = __float_as_uint(f);
    u += 0x7FFFu + ((u >> 16) & 1u);   // RNE
    return (unsigned short)(u >> 16);
}
__device__ __forceinline__ float bf2f(unsigned short h) {
    return __uint_as_float(((unsigned)h) << 16);
}
__device__ __forceinline__ float rcp_(float x) { return __builtin_amdgcn_rcpf(x); }
__device__ __forceinline__ float sigmoidf_(float x) {
    return rcp_(1.0f + __expf(-x));
}
__device__ __forceinline__ float tanhf_(float x) {
    float ax = fabsf(x);
    float e = __expf(-2.0f * ax);
    float t = (1.0f - e) * rcp_(1.0f + e);
    return copysignf(t, x);
}

// Fragment-order layouts (A-operand of mfma_f32_16x16x32_bf16):
//   chunk(c) = 1024 B covering 16 rows x 32 k; lane l = 16*kchunk + row15
//   holds 8 bf16 (k = kt*32 + kchunk*8 + j) at byte l*16 + j*2.
// cB2  chunks: ((mtile*9 + kt)*8 + m16)        mtile=r>>7, m16=(r&127)>>4
// WT2b chunks: ((ntile*9 + kt)*8 + v16)        v = virtual gate col

// ---------------- K1: prep: swizzled cB2 / WT2b, WbT2, lastc, out-init ------
__global__ __launch_bounds__(256) void prep(
    const float* __restrict__ X, const float* __restrict__ emb,
    const float* __restrict__ Wn, const float* __restrict__ bn,
    const float* __restrict__ Wf, const float* __restrict__ bfv,
    const float* __restrict__ Wb, const float* __restrict__ bb,
    const float* __restrict__ bo,
    unsigned short* __restrict__ cB2, unsigned short* __restrict__ WT2b,
    unsigned short* __restrict__ WbT2, unsigned short* __restrict__ lastc,
    float* __restrict__ out) {
    int bid = blockIdx.x;
    int tid = threadIdx.x;
    int wave = tid >> 6, lane = tid & 63;

    if (bid < 8192) {                       // ---- c rows -> swizzled cB2
        int r = bid * 4 + wave;
        const float* xr = X + (size_t)r * 8;
        int ev = (int)xr[0];
        float4 e4 = *(const float4*)(emb + (size_t)ev * EMB_ + lane * 4);
        unsigned short p[4] = {f2bf(e4.x), f2bf(e4.y), f2bf(e4.z), f2bf(e4.w)};
        int kt = lane >> 3;
        int kchunk = (lane >> 1) & 3;
        int j = (lane & 1) * 4;
        size_t chunk = ((size_t)(r >> 7) * 9 + kt) * 8 + ((r & 127) >> 4);
        *(uint2*)(cB2 + chunk * 512 + (16 * kchunk + (r & 15)) * 8 + j) =
            *(const uint2*)p;
        int isLast = ((r & 511) == 511);
        if (isLast) {
            int b = r >> 9;
            *(uint2*)(lastc + (size_t)b * 264 + 4 * lane) = *(const uint2*)p;
        }
        if (lane < 16) {                    // tail k = 256 + 2*lane (+1)
            unsigned short a01[2];
#pragma unroll
            for (int h = 0; h < 2; ++h) {
                int e = 256 + 2 * lane + h;
                unsigned short res = 0;
                if (e < D_) {
                    int jj = e - 256;
                    float v = bn[jj];
#pragma unroll
                    for (int i = 0; i < NIN_; ++i) v += xr[1 + i] * Wn[i * NOUT_ + jj];
                    res = f2bf(v);
                } else if (e == D_) {
                    res = 0x3F80;           // 1.0 -> picks up bias row
                }
                a01[h] = res;
            }
            unsigned pk = (unsigned)a01[0] | ((unsigned)a01[1] << 16);
            int kc2 = (lane >> 2) & 3;      // ((256+2l)>>3)&3
            int j2 = (2 * lane) & 7;
            size_t chunk8 = ((size_t)(r >> 7) * 9 + 8) * 8 + ((r & 127) >> 4);
            *(unsigned*)(cB2 + chunk8 * 512 + (16 * kc2 + (r & 15)) * 8 + j2) = pk;
            if (isLast && lane < 4)
                *(unsigned*)(lastc + (size_t)(r >> 9) * 264 + 256 + 2 * lane) = pk;
        }
    } else if (bid < 8448) {                // ---- Wf -> swizzled WT2b
        int v = (bid - 8192) * 4 + wave;    // 0..1023 virtual col
        int r7 = v & 127;
        int jcol = (v >> 7) * 64 + (r7 & 63);
        int col = (r7 < 64) ? jcol : (512 + jcol);
        unsigned short p[4];
        int k0 = 4 * lane;
#pragma unroll
        for (int q = 0; q < 4; ++q) {
            int k = k0 + q;
            p[q] = (k < D_) ? f2bf(Wf[(size_t)k * 1536 + col])
                 : (k == D_) ? f2bf(bfv[col]) : (unsigned short)0;
        }
        int kt = lane >> 3;
        int kchunk = (lane >> 1) & 3;
        int j = (lane & 1) * 4;
        size_t chunk = ((size_t)(v >> 7) * 9 + kt) * 8 + (r7 >> 4);
        *(uint2*)(WT2b + chunk * 512 + (16 * kchunk + (v & 15)) * 8 + j) =
            *(const uint2*)p;
        if (lane < 8) {                     // tail k = 256 + 4*lane .. +3
            int kb = 256 + 4 * lane;
#pragma unroll
            for (int q = 0; q < 4; ++q) {
                int k = kb + q;
                p[q] = (k < D_) ? f2bf(Wf[(size_t)k * 1536 + col])
                     : (k == D_) ? f2bf(bfv[col]) : (unsigned short)0;
            }
            int kc2 = (lane >> 1) & 3;
            int j2 = (lane & 1) * 4;
            size_t chunk8 = ((size_t)(v >> 7) * 9 + 8) * 8 + (r7 >> 4);
            *(uint2*)(WT2b + chunk8 * 512 + (16 * kc2 + (v & 15)) * 8 + j2) =
                *(const uint2*)p;
        }
    } else if (bid < 8704) {                // ---- Wb -> plain WbT2[n][288]
        int n = (bid - 8448) * 4 + wave;    // 0..1023 direct Wb column
        unsigned short p[4];
        int k0 = 4 * lane;
#pragma unroll
        for (int q = 0; q < 4; ++q) {
            int k = k0 + q;
            p[q] = (k < D_) ? f2bf(Wb[(size_t)k * 1536 + n])
                 : (k == D_) ? f2bf(bb[n]) : (unsigned short)0;
        }
        *(uint2*)(WbT2 + (size_t)n * KP_ + k0) = *(const uint2*)p;
        if (lane < 8) {
            int kb = 256 + 4 * lane;
#pragma unroll
            for (int q = 0; q < 4; ++q) {
                int k = kb + q;
                p[q] = (k < D_) ? f2bf(Wb[(size_t)k * 1536 + n])
                     : (k == D_) ? f2bf(bb[n]) : (unsigned short)0;
            }
            *(uint2*)(WbT2 + (size_t)n * KP_ + kb) = *(const uint2*)p;
        }
    } else {                                // ---- init out to bo
        if (tid < B_) out[tid] = bo[0];
    }
}

// ---------------- K2: barrier-free GEMM K-loop + in-LDS chunk scan ----------
// grid 2048: mtile = bid%256 (XCD L2 locality), ntile = bid/256.
// K-loop: register-double-buffered global_load_dwordx4 -> MFMA, no LDS.
__global__ __launch_bounds__(256) void gemm_scan(
    const unsigned short* __restrict__ cB2, const unsigned short* __restrict__ WT2b,
    float* __restrict__ PQ) {
    __shared__ __align__(16) unsigned short L[19456];      // 38,912 B
    int bid = blockIdx.x;
    int mtile = bid & 255;
    int ntile = bid >> 8;
    int r0 = mtile * 128;
    int tid = threadIdx.x;
    int lane = tid & 63, wave = tid >> 6;
    int wm = wave & 1, wn = wave >> 1;
    int rl = lane & 15;

    const unsigned short* pa =
        cB2 + (((size_t)mtile * 9) * 8 + 4 * wm) * 512 + lane * 8;
    const unsigned short* pb =
        WT2b + (((size_t)ntile * 9) * 8 + 4 * wn) * 512 + lane * 8;

    floatx4 acc[4][4];
#pragma unroll
    for (int mi = 0; mi < 4; ++mi)
#pragma unroll
        for (int ni = 0; ni < 4; ++ni) acc[mi][ni] = (floatx4){0.f, 0.f, 0.f, 0.f};

    bf16x8 afc[4], bfc[4], afn[4], bfn[4];
#pragma unroll
    for (int mi = 0; mi < 4; ++mi) afc[mi] = *(const bf16x8*)(pa + mi * 512);
#pragma unroll
    for (int ni = 0; ni < 4; ++ni) bfc[ni] = *(const bf16x8*)(pb + ni * 512);

#pragma unroll
    for (int kt = 0; kt < 9; ++kt) {
        if (kt < 8) {
#pragma unroll
            for (int mi = 0; mi < 4; ++mi)
                afn[mi] = *(const bf16x8*)(pa + (size_t)(kt + 1) * 4096 + mi * 512);
#pragma unroll
            for (int ni = 0; ni < 4; ++ni)
                bfn[ni] = *(const bf16x8*)(pb + (size_t)(kt + 1) * 4096 + ni * 512);
        }
#pragma unroll
        for (int mi = 0; mi < 4; ++mi)
#pragma unroll
            for (int ni = 0; ni < 4; ++ni)
                acc[mi][ni] = __builtin_amdgcn_mfma_f32_16x16x32_bf16(afc[mi], bfc[ni], acc[mi][ni], 0, 0, 0);
        if (kt < 8) {
#pragma unroll
            for (int mi = 0; mi < 4; ++mi) afc[mi] = afn[mi];
#pragma unroll
            for (int ni = 0; ni < 4; ++ni) bfc[ni] = bfn[ni];
        }
    }

    // ---- epilogue: pack acc -> Gt[col][row], stride 132
    // C/D: col = lane&15, row = (lane>>4)*4 + reg  [m89/m91]
#pragma unroll
    for (int ni = 0; ni < 4; ++ni) {
        int lc = 64 * wn + 16 * ni + rl;       // local virtual col 0..127
#pragma unroll
        for (int mi = 0; mi < 4; ++mi) {
            int lrb = 64 * wm + 16 * mi + (lane >> 4) * 4;
            unsigned short p[4];
#pragma unroll
            for (int v = 0; v < 4; ++v) p[v] = f2bf(acc[mi][ni][v]);
            *(uint2*)(L + (size_t)lc * 132 + lrb) = *(const uint2*)p;
        }
    }
    __syncthreads();

    // ---- scan: thread (c = tid>>6, j = tid&63) scans subchunk c' (32 steps)
    {
        int j = tid & 63, c = tid >> 6;
        int cp = (c + (j >> 4)) & 3;        // permuted subchunk: 2-way banks
        float P = 1.f, Q = 0.f;
        const unsigned short* zp = L + (size_t)j * 132 + cp * 32;
        const unsigned short* fp = L + (size_t)(64 + j) * 132 + cp * 32;
#pragma unroll
        for (int u = 0; u < 8; ++u) {
            u16x4 zv = *(const u16x4*)(zp + 4 * u);
            u16x4 fv = *(const u16x4*)(fp + 4 * u);
#pragma unroll
            for (int t = 0; t < 4; ++t) {
                float z = tanhf_(bf2f(zv[t]));
                float f = sigmoidf_(bf2f(fv[t]));
                Q = f * Q + (1.f - f) * z;
                P *= f;
            }
        }
        float* SpP = (float*)((char*)L + 36864);
        float* SpQ = SpP + 256;
        SpP[cp * 64 + j] = P;
        SpQ[cp * 64 + j] = Q;
        __syncthreads();
        if (tid < 64) {
            float Pt = 1.f, Qt = 0.f;
#pragma unroll
            for (int cc = 0; cc < 4; ++cc) {
                float p = SpP[cc * 64 + tid];
                float q = SpQ[cc * 64 + tid];
                Qt = p * Qt + q;
                Pt *= p;
            }
            int b = r0 >> 9;
            int chm = (r0 >> 7) & 3;
            size_t idx = ((size_t)(b * 4 + chm) * 512 + ntile * 64 + tid);
            ((float2*)PQ)[idx] = make_float2(Pt, Qt);
        }
    }
}

// ---------------- K3: fold chunks + backward row + Wo dot -------------------
__global__ __launch_bounds__(256) void final_out(
    const unsigned short* __restrict__ lastc, const unsigned short* __restrict__ WbT2,
    const float* __restrict__ Wo, const float* __restrict__ PQ,
    float* __restrict__ out) {
    int blk = blockIdx.x;                    // 0..127 (2 blocks per b)
    int b = blk >> 1;
    int jg = (blk & 1) * 256 + threadIdx.x;  // 0..511

    float h = 0.f;
#pragma unroll
    for (int c = 0; c < 4; ++c) {
        float2 pq = ((const float2*)PQ)[(size_t)(b * 4 + c) * 512 + jg];
        h = pq.x * h + pq.y;
    }

    __shared__ __align__(16) unsigned short crow[264];
    if (threadIdx.x < 33)
        *(u16x8*)(crow + threadIdx.x * 8) =
            *(const u16x8*)(lastc + (size_t)b * 264 + threadIdx.x * 8);
    __syncthreads();

    const unsigned short* wz = WbT2 + (size_t)jg * KP_;
    const unsigned short* wf = WbT2 + (size_t)(512 + jg) * KP_;
    float gz = 0.f, gf = 0.f;                // bias folded at k=260
#pragma unroll 4
    for (int u = 0; u < 33; ++u) {           // k = 0..263 (264..287 are zero)
        u16x8 cv8 = *(const u16x8*)(crow + 8 * u);
        u16x8 wz8 = *(const u16x8*)(wz + 8 * u);
        u16x8 wf8 = *(const u16x8*)(wf + 8 * u);
#pragma unroll
        for (int t = 0; t < 8; ++t) {
            float cv = bf2f(cv8[t]);
            gz += cv * bf2f(wz8[t]);
            gf += cv * bf2f(wf8[t]);
        }
    }
    float hb = (1.f - sigmoidf_(gf)) * tanhf_(gz);

    float partial = h * Wo[jg] + hb * Wo[512 + jg];
    __shared__ float red[256];
    red[threadIdx.x] = partial;
    __syncthreads();
    for (int off = 128; off > 0; off >>= 1) {
        if (threadIdx.x < off) red[threadIdx.x] += red[threadIdx.x + off];
        __syncthreads();
    }
    if (threadIdx.x == 0) atomicAdd(out + b, red[0]);
}

extern "C" void kernel_launch(void* const* d_in, const int* in_sizes, int n_in,
                              void* d_out, int out_size, void* d_ws, size_t ws_size,
                              hipStream_t stream) {
    const float* X   = (const float*)d_in[0];
    const float* emb = (const float*)d_in[1];
    const float* Wn  = (const float*)d_in[2];
    const float* bn  = (const float*)d_in[3];
    const float* Wf  = (const float*)d_in[4];
    const float* bfv = (const float*)d_in[5];
    const float* Wb  = (const float*)d_in[6];
    const float* bb  = (const float*)d_in[7];
    const float* Wo  = (const float*)d_in[8];
    const float* bo  = (const float*)d_in[9];
    float* out = (float*)d_out;

    size_t off_cB2 = 0;
    size_t off_WT  = off_cB2 + (size_t)M_ * KP_ * 2;          // 18,874,368
    size_t off_WbT = off_WT + (size_t)1024 * KP_ * 2;         // +589,824
    size_t off_lc  = off_WbT + (size_t)1024 * KP_ * 2;        // +589,824
    size_t off_PQ  = off_lc + (size_t)B_ * 264 * 2;           // +33,792
    size_t need    = off_PQ + (size_t)B_ * 4 * 512 * 2 * sizeof(float);  // +1 MB
    if (ws_size < need) return;

    unsigned short* cB2  = (unsigned short*)((char*)d_ws + off_cB2);
    unsigned short* WT2b = (unsigned short*)((char*)d_ws + off_WT);
    unsigned short* WbT2 = (unsigned short*)((char*)d_ws + off_WbT);
    unsigned short* lastc= (unsigned short*)((char*)d_ws + off_lc);
    float*          PQ   = (float*)((char*)d_ws + off_PQ);

    prep<<<8705, 256, 0, stream>>>(X, emb, Wn, bn, Wf, bfv, Wb, bb, bo,
                                   cB2, WT2b, WbT2, lastc, out);
    gemm_scan<<<2048, 256, 0, stream>>>(cB2, WT2b, PQ);
    final_out<<<128, 256, 0, stream>>>(lastc, WbT2, Wo, PQ, out);
}

// Round 5
// 114.197 us; speedup vs baseline: 1.6119x; 1.1213x over previous
//
#include <hip/hip_runtime.h>
#include <stdint.h>

#define B_ 64
#define S_ 512
#define EMB_ 256
#define NIN_ 7
#define NOUT_ 4
#define HID_ 512
#define VOCAB_ 1000
#define VP_ 1024          // vocab padded to 1024 rows
#define NG_ 2048          // table cols: [fwd z/f interleaved 1024 | bwd 1024]
#define M_ (B_ * S_)

typedef __bf16 bf16x8 __attribute__((ext_vector_type(8)));
typedef float floatx4 __attribute__((ext_vector_type(4)));
typedef unsigned short u16x8 __attribute__((ext_vector_type(8)));

__device__ __forceinline__ unsigned short f2bf(float f) {
    unsigned u = __float_as_uint(f);
    u += 0x7FFFu + ((u >> 16) & 1u);   // RNE
    return (unsigned short)(u >> 16);
}
__device__ __forceinline__ float bf2f(unsigned short h) {
    return __uint_as_float(((unsigned)h) << 16);
}
__device__ __forceinline__ float rcp_(float x) { return __builtin_amdgcn_rcpf(x); }
__device__ __forceinline__ float sigmoidf_(float x) {
    return rcp_(1.0f + __expf(-x));
}
__device__ __forceinline__ float tanhf_(float x) {
    float ax = fabsf(x);
    float e = __expf(-2.0f * ax);
    float t = (1.0f - e) * rcp_(1.0f + e);
    return copysignf(t, x);
}

// virtual table col v (0..2047): part = v>>10 (0 fwd Wf, 1 bwd Wb),
// m = v&1023, j = m>>1, zf = m&1, source col c = zf ? 512+j : j.
// G[row][2j] = z-gate, G[row][2j+1] = f-gate (fwd); +1024 for bwd.

// MFMA fragment-order chunks (identical scheme to R4, K=256 -> 8 kt):
//   chunk = ((tile*8 + kt)*8 + grp16)*512 shorts; lane l = 16*kchunk + idx15
//   holds 8 bf16 (k = kt*32 + kchunk*8 + q) at short offset l*8 + q.

// ---------------- K1: prep: Aemb frags, WT frags, W7/bvec -------------------
__global__ __launch_bounds__(256) void prep(
    const float* __restrict__ emb, const float* __restrict__ Wn,
    const float* __restrict__ bn, const float* __restrict__ Wf,
    const float* __restrict__ bfv, const float* __restrict__ Wb,
    const float* __restrict__ bb,
    unsigned short* __restrict__ Aemb, unsigned short* __restrict__ WT,
    float* __restrict__ W7, float* __restrict__ bvec) {
    int bid = blockIdx.x;
    int tid = threadIdx.x;

    if (bid < 64) {                         // ---- Aemb: rows 16*bid..+15
        int g = bid;
#pragma unroll
        for (int half = 0; half < 2; ++half) {
            int t = tid + 256 * half;
            int r15 = t & 15;
            int kchunk = (t >> 4) & 3;
            int kt = t >> 6;                // 0..7
            int row = g * 16 + r15;
            int k0 = kt * 32 + kchunk * 8;
            unsigned short p[8];
            if (row < VOCAB_) {
                float4 a = *(const float4*)(emb + (size_t)row * EMB_ + k0);
                float4 b = *(const float4*)(emb + (size_t)row * EMB_ + k0 + 4);
                p[0]=f2bf(a.x); p[1]=f2bf(a.y); p[2]=f2bf(a.z); p[3]=f2bf(a.w);
                p[4]=f2bf(b.x); p[5]=f2bf(b.y); p[6]=f2bf(b.z); p[7]=f2bf(b.w);
            } else {
#pragma unroll
                for (int q = 0; q < 8; ++q) p[q] = 0;
            }
            size_t chunk = ((size_t)(g >> 3) * 8 + kt) * 8 + (g & 7);
            *(u16x8*)(Aemb + chunk * 512 + (16 * kchunk + r15) * 8) =
                *(const u16x8*)p;
        }
    } else if (bid < 192) {                 // ---- WT: cols 16*(bid-64)..+15
        int g = bid - 64;
#pragma unroll
        for (int half = 0; half < 2; ++half) {
            int t = tid + 256 * half;
            int v15 = t & 15;
            int kchunk = (t >> 4) & 3;
            int kt = t >> 6;
            int v = g * 16 + v15;
            int part = v >> 10;
            int m = v & 1023;
            int j = m >> 1;
            int c = (m & 1) ? (512 + j) : j;
            const float* W = part ? Wb : Wf;
            int k0 = kt * 32 + kchunk * 8;
            unsigned short p[8];
#pragma unroll
            for (int q = 0; q < 8; ++q)
                p[q] = f2bf(W[(size_t)(k0 + q) * 1536 + c]);
            size_t chunk = ((size_t)(g >> 3) * 8 + kt) * 8 + (g & 7);
            *(u16x8*)(WT + chunk * 512 + (16 * kchunk + v15) * 8) =
                *(const u16x8*)p;
        }
    } else {                                // ---- W7 (7 x 2048) + bvec (2048)
        float wn[NIN_][NOUT_];
#pragma unroll
        for (int i = 0; i < NIN_; ++i)
#pragma unroll
            for (int q = 0; q < NOUT_; ++q) wn[i][q] = Wn[i * NOUT_ + q];
        float bnr[NOUT_];
#pragma unroll
        for (int q = 0; q < NOUT_; ++q) bnr[q] = bn[q];
#pragma unroll
        for (int it = 0; it < 8; ++it) {
            int v = tid + 256 * it;
            int part = v >> 10;
            int m = v & 1023;
            int j = m >> 1;
            int c = (m & 1) ? (512 + j) : j;
            const float* W = part ? Wb : Wf;
            float wnum[NOUT_];
#pragma unroll
            for (int q = 0; q < NOUT_; ++q)
                wnum[q] = W[(size_t)(256 + q) * 1536 + c];
            float bv = part ? bb[c] : bfv[c];
#pragma unroll
            for (int q = 0; q < NOUT_; ++q) bv += bnr[q] * wnum[q];
            bvec[v] = bv;
#pragma unroll
            for (int i = 0; i < NIN_; ++i) {
                float s = 0.f;
#pragma unroll
                for (int q = 0; q < NOUT_; ++q) s += wn[i][q] * wnum[q];
                W7[(size_t)i * NG_ + v] = s;
            }
        }
    }
}

// ---------------- K2: G = Aemb @ WT + bvec (1024 x 2048, K=256) -------------
// barrier-free register-double-buffered K-loop (R4 structure, 8 kt).
__global__ __launch_bounds__(256) void gemmG(
    const unsigned short* __restrict__ Aemb, const unsigned short* __restrict__ WT,
    const float* __restrict__ bvec, unsigned short* __restrict__ G) {
    int bid = blockIdx.x;                   // 128 = 8 mtiles x 16 ntiles
    int mtile = bid & 7;
    int ntile = bid >> 3;
    int r0 = mtile * 128;
    int n0 = ntile * 128;
    int tid = threadIdx.x;
    int lane = tid & 63, wave = tid >> 6;
    int wm = wave & 1, wn = wave >> 1;
    int rl = lane & 15;

    const unsigned short* pa = Aemb + ((size_t)mtile * 64 + 4 * wm) * 512 + lane * 8;
    const unsigned short* pb = WT + ((size_t)ntile * 64 + 4 * wn) * 512 + lane * 8;

    floatx4 acc[4][4];
#pragma unroll
    for (int mi = 0; mi < 4; ++mi)
#pragma unroll
        for (int ni = 0; ni < 4; ++ni) acc[mi][ni] = (floatx4){0.f, 0.f, 0.f, 0.f};

    bf16x8 afc[4], bfc[4], afn[4], bfn[4];
#pragma unroll
    for (int mi = 0; mi < 4; ++mi) afc[mi] = *(const bf16x8*)(pa + mi * 512);
#pragma unroll
    for (int ni = 0; ni < 4; ++ni) bfc[ni] = *(const bf16x8*)(pb + ni * 512);

#pragma unroll
    for (int kt = 0; kt < 8; ++kt) {
        if (kt < 7) {
#pragma unroll
            for (int mi = 0; mi < 4; ++mi)
                afn[mi] = *(const bf16x8*)(pa + (size_t)(kt + 1) * 4096 + mi * 512);
#pragma unroll
            for (int ni = 0; ni < 4; ++ni)
                bfn[ni] = *(const bf16x8*)(pb + (size_t)(kt + 1) * 4096 + ni * 512);
        }
#pragma unroll
        for (int mi = 0; mi < 4; ++mi)
#pragma unroll
            for (int ni = 0; ni < 4; ++ni)
                acc[mi][ni] = __builtin_amdgcn_mfma_f32_16x16x32_bf16(afc[mi], bfc[ni], acc[mi][ni], 0, 0, 0);
        if (kt < 7) {
#pragma unroll
            for (int mi = 0; mi < 4; ++mi) afc[mi] = afn[mi];
#pragma unroll
            for (int ni = 0; ni < 4; ++ni) bfc[ni] = bfn[ni];
        }
    }

    // C/D: col = lane&15, row = (lane>>4)*4 + reg  [m89/m91]
#pragma unroll
    for (int ni = 0; ni < 4; ++ni) {
        int n = n0 + 64 * wn + 16 * ni + rl;
        float bv = bvec[n];
#pragma unroll
        for (int mi = 0; mi < 4; ++mi) {
            int rb = r0 + 64 * wm + 16 * mi + (lane >> 4) * 4;
#pragma unroll
            for (int v = 0; v < 4; ++v)
                G[(size_t)(rb + v) * NG_ + n] = f2bf(acc[mi][ni][v] + bv);
        }
    }
}

// ---------------- K3: gather-scan: 512 blocks (b x 8 chunks) x 512 thr ------
__global__ __launch_bounds__(512) void scan(
    const float* __restrict__ X, const unsigned short* __restrict__ G,
    const float* __restrict__ W7, float* __restrict__ PQ) {
    __shared__ float LX[512];               // 64 steps x 8 floats
    int bid = blockIdx.x;
    int b = bid >> 3, chunk = bid & 7;
    int s0 = chunk * 64;
    int j = threadIdx.x;                    // chain 0..511

    LX[j] = X[((size_t)b * S_ + s0 + (j >> 3)) * 8 + (j & 7)];
    __syncthreads();

    float2 w7p[NIN_];
#pragma unroll
    for (int i = 0; i < NIN_; ++i)
        w7p[i] = *(const float2*)(W7 + (size_t)i * NG_ + 2 * j);

    float P = 1.f, Q = 0.f;
    int ev0 = (int)LX[0];
    unsigned gp = *(const unsigned*)(G + (size_t)ev0 * NG_ + 2 * j);
#pragma unroll 4
    for (int s = 0; s < 64; ++s) {
        unsigned gpc = gp;
        if (s < 63) {
            int evn = (int)LX[(s + 1) * 8];
            gp = *(const unsigned*)(G + (size_t)evn * NG_ + 2 * j);
        }
        float gz = bf2f((unsigned short)(gpc & 0xffffu));
        float gf = bf2f((unsigned short)(gpc >> 16));
#pragma unroll
        for (int i = 0; i < NIN_; ++i) {
            float x = LX[s * 8 + 1 + i];
            gz += x * w7p[i].x;
            gf += x * w7p[i].y;
        }
        float z = tanhf_(gz);
        float f = sigmoidf_(gf);
        Q = f * Q + (1.f - f) * z;
        P *= f;
    }
    ((float2*)PQ)[(size_t)bid * 512 + j] = make_float2(P, Q);
}

// ---------------- K4: fold chunks + backward (1 step) + Wo dot --------------
__global__ __launch_bounds__(512) void final_out(
    const float* __restrict__ X, const unsigned short* __restrict__ G,
    const float* __restrict__ W7, const float* __restrict__ Wo,
    const float* __restrict__ bo, const float* __restrict__ PQ,
    float* __restrict__ out) {
    int b = blockIdx.x;
    int j = threadIdx.x;                    // 0..511

    float h = 0.f;
#pragma unroll
    for (int c = 0; c < 8; ++c) {
        float2 pq = ((const float2*)PQ)[((size_t)b * 8 + c) * 512 + j];
        h = pq.x * h + pq.y;
    }

    const float* xr = X + ((size_t)b * S_ + (S_ - 1)) * 8;
    int ev = (int)xr[0];
    unsigned gpc = *(const unsigned*)(G + (size_t)ev * NG_ + 1024 + 2 * j);
    float gz = bf2f((unsigned short)(gpc & 0xffffu));
    float gf = bf2f((unsigned short)(gpc >> 16));
#pragma unroll
    for (int i = 0; i < NIN_; ++i) {
        float2 w = *(const float2*)(W7 + (size_t)i * NG_ + 1024 + 2 * j);
        float x = xr[1 + i];
        gz += x * w.x;
        gf += x * w.y;
    }
    float hb = (1.f - sigmoidf_(gf)) * tanhf_(gz);

    float partial = h * Wo[j] + hb * Wo[512 + j];
    __shared__ float red[512];
    red[j] = partial;
    __syncthreads();
    for (int off = 256; off > 0; off >>= 1) {
        if (j < off) red[j] += red[j + off];
        __syncthreads();
    }
    if (j == 0) out[b] = red[0] + bo[0];
}

extern "C" void kernel_launch(void* const* d_in, const int* in_sizes, int n_in,
                              void* d_out, int out_size, void* d_ws, size_t ws_size,
                              hipStream_t stream) {
    const float* X   = (const float*)d_in[0];
    const float* emb = (const float*)d_in[1];
    const float* Wn  = (const float*)d_in[2];
    const float* bn  = (const float*)d_in[3];
    const float* Wf  = (const float*)d_in[4];
    const float* bfv = (const float*)d_in[5];
    const float* Wb  = (const float*)d_in[6];
    const float* bb  = (const float*)d_in[7];
    const float* Wo  = (const float*)d_in[8];
    const float* bo  = (const float*)d_in[9];
    float* out = (float*)d_out;

    size_t off_A  = 0;
    size_t off_WT = off_A  + (size_t)VP_ * EMB_ * 2;          // 512 KB
    size_t off_G  = off_WT + (size_t)NG_ * EMB_ * 2;          // +1 MB
    size_t off_W7 = off_G  + (size_t)VP_ * NG_ * 2;           // +4 MB
    size_t off_bv = off_W7 + (size_t)NIN_ * NG_ * 4;          // +56 KB
    size_t off_PQ = off_bv + (size_t)NG_ * 4;                 // +8 KB
    size_t need   = off_PQ + (size_t)B_ * 8 * 512 * 2 * sizeof(float);  // +2 MB
    if (ws_size < need) return;

    unsigned short* Aemb = (unsigned short*)((char*)d_ws + off_A);
    unsigned short* WT   = (unsigned short*)((char*)d_ws + off_WT);
    unsigned short* G    = (unsigned short*)((char*)d_ws + off_G);
    float*          W7   = (float*)((char*)d_ws + off_W7);
    float*          bvec = (float*)((char*)d_ws + off_bv);
    float*          PQ   = (float*)((char*)d_ws + off_PQ);

    prep<<<193, 256, 0, stream>>>(emb, Wn, bn, Wf, bfv, Wb, bb,
                                  Aemb, WT, W7, bvec);
    gemmG<<<128, 256, 0, stream>>>(Aemb, WT, bvec, G);
    scan<<<512, 512, 0, stream>>>(X, G, W7, PQ);
    final_out<<<64, 512, 0, stream>>>(X, G, W7, Wo, bo, PQ, out);
}